// Round 1
// baseline (558.343 us; speedup 1.0000x reference)
//
#include <hip/hip_runtime.h>

#define NN 1024
#define DD 128
#define NBLK 256

typedef __attribute__((ext_vector_type(8))) __bf16 bf16x8;
typedef __attribute__((ext_vector_type(4))) float f32x4;

__device__ __forceinline__ float us2f(unsigned short b) { return __uint_as_float(((unsigned)b) << 16); }
__device__ __forceinline__ unsigned short f2bf(float f) {
    unsigned x = __float_as_uint(f);
    return (unsigned short)((x + 0x7fffu + ((x >> 16) & 1u)) >> 16);   // RNE
}

// Grid barrier: monotonic 16-way split counters (128B-spaced lines), device scope.
// All 256 blocks are co-resident by construction (grid == #CUs, <=2 blocks/CU capacity),
// so spinning is safe. Fences give agent-scope (cross-XCD) visibility.
__device__ __forceinline__ void gridbar(unsigned* cnt, unsigned epoch) {
    __syncthreads();
    __threadfence();                                   // release: publish this block's writes
    int tid = threadIdx.x;
    if (tid == 0)
        __hip_atomic_fetch_add(&cnt[(blockIdx.x & 15) << 5], 1u,
                               __ATOMIC_RELEASE, __HIP_MEMORY_SCOPE_AGENT);
    if (tid < 16) {
        unsigned tgt = epoch << 4;                     // 16 blocks feed each sub-counter
        while (__hip_atomic_load(&cnt[tid << 5],
                                 __ATOMIC_ACQUIRE, __HIP_MEMORY_SCOPE_AGENT) < tgt)
            __builtin_amdgcn_s_sleep(1);
    }
    __threadfence();                                   // acquire: invalidate stale lines
    __syncthreads();
}

__global__ __launch_bounds__(256) void k_fused(
    const float* __restrict__ adj, const float* __restrict__ ew,
    const float* __restrict__ nf, const float* __restrict__ We, const float* __restrict__ be,
    const float* __restrict__ Wu, const float* __restrict__ bu,
    const float* __restrict__ Wv, const float* __restrict__ bv,
    const float* __restrict__ Wg, const float* __restrict__ bg,
    const float* __restrict__ Wc1, const float* __restrict__ bc1,
    const float* __restrict__ Wc2, const float* __restrict__ bc2,
    float* __restrict__ h, float* __restrict__ u,
    unsigned short* __restrict__ vTh, unsigned short* __restrict__ vTl,
    float* __restrict__ P,
    unsigned short* __restrict__ adjH, unsigned short* __restrict__ adjL,
    float* __restrict__ hi, float* __restrict__ hj,
    float* __restrict__ S1, float* __restrict__ S2,
    float* __restrict__ lossAcc, unsigned* __restrict__ barCnt,
    float* __restrict__ outL)
{
    __shared__ union SMem {
        float hS4[4][DD];                                              // phase 0 (embed)
        struct { float uS[4][DD], aS[4][DD], hS[4][DD], sred[2][4]; } g;  // gate phases
        struct { float hiT[128][68], hjT[128][68], wS[128], lred; } e;    // edge phase
    } sm;

    int tid = threadIdx.x;
    int bx = blockIdx.x;
    int d = tid & 127, half = tid >> 7;
    unsigned ep = 0;

    // ---------------- Phase 0: adj -> bf16 split (tasks 0..1023) | embed + layer-0 u/v (tasks 1024..1279)
    for (int t = bx; t < 1280; t += NBLK) {
        if (t < 1024) {
            int idx = (t * 256 + tid) * 4;
            float4 a = *(const float4*)(adj + idx);
            ushort4 hv, lv;
            hv.x = f2bf(a.x); lv.x = f2bf(a.x - us2f(hv.x));
            hv.y = f2bf(a.y); lv.y = f2bf(a.y - us2f(hv.y));
            hv.z = f2bf(a.z); lv.z = f2bf(a.z - us2f(hv.z));
            hv.w = f2bf(a.w); lv.w = f2bf(a.w - us2f(hv.w));
            *(ushort4*)(adjH + idx) = hv;
            *(ushort4*)(adjL + idx) = lv;
        } else {
            int m0 = (t - 1024) * 4;
            float hr[4];
#pragma unroll
            for (int r = 0; r < 4; ++r) {
                float a = be[d];
#pragma unroll
                for (int k = 0; k < 3; ++k) a = fmaf(nf[(m0 + r) * 3 + k], We[k * DD + d], a);
                hr[r] = a;
            }
            if (half == 0) {
#pragma unroll
                for (int r = 0; r < 4; ++r) { h[(m0 + r) * DD + d] = hr[r]; sm.hS4[r][d] = hr[r]; }
            }
            __syncthreads();
            const float* W = half ? Wv : Wu;
            float acc[4] = {0.f, 0.f, 0.f, 0.f};
#pragma unroll 4
            for (int k4 = 0; k4 < DD; k4 += 4) {
                f32x4 h0 = *(const f32x4*)&sm.hS4[0][k4];
                f32x4 h1 = *(const f32x4*)&sm.hS4[1][k4];
                f32x4 h2 = *(const f32x4*)&sm.hS4[2][k4];
                f32x4 h3 = *(const f32x4*)&sm.hS4[3][k4];
#pragma unroll
                for (int kk = 0; kk < 4; ++kk) {
                    float w = W[(k4 + kk) * DD + d];
                    acc[0] = fmaf(h0[kk], w, acc[0]);
                    acc[1] = fmaf(h1[kk], w, acc[1]);
                    acc[2] = fmaf(h2[kk], w, acc[2]);
                    acc[3] = fmaf(h3[kk], w, acc[3]);
                }
            }
            if (half == 0) {
                float bb = bu[d];
#pragma unroll
                for (int r = 0; r < 4; ++r) u[(m0 + r) * DD + d] = acc[r] + bb;
            } else {
                float bb = bv[d];
                float v0 = acc[0] + bb, v1 = acc[1] + bb, v2 = acc[2] + bb, v3 = acc[3] + bb;
                ushort4 hv, lv;
                hv.x = f2bf(v0); lv.x = f2bf(v0 - us2f(hv.x));
                hv.y = f2bf(v1); lv.y = f2bf(v1 - us2f(hv.y));
                hv.z = f2bf(v2); lv.z = f2bf(v2 - us2f(hv.z));
                hv.w = f2bf(v3); lv.w = f2bf(v3 - us2f(hv.w));
                *(ushort4*)(vTh + d * NN + m0) = hv;
                *(ushort4*)(vTl + d * NN + m0) = lv;
            }
        }
    }
    gridbar(barCnt, ++ep);

    // ---------------- 3 GCN layers
    for (int l = 0; l < 3; ++l) {
        // ---- agg partials: P[kc] = adj[:, kc-chunk] @ v[kc-chunk, :]  (1024 tasks, MFMA split-precision)
        {
            int lane = tid & 63, w = tid >> 6;
            for (int t = bx; t < 1024; t += NBLK) {
                int nt = t >> 7;
                int mt = (t >> 1) & 63;
                int kc = ((t & 1) << 2) | w;
                int m = lane & 15, quad = lane >> 4;
                int k0 = kc * 128 + quad * 8;
                const unsigned short* ah = adjH + (size_t)(mt * 16 + m) * NN + k0;
                const unsigned short* al = adjL + (size_t)(mt * 16 + m) * NN + k0;
                const unsigned short* bh = vTh + (size_t)(nt * 16 + m) * NN + k0;
                const unsigned short* bl = vTl + (size_t)(nt * 16 + m) * NN + k0;
                f32x4 acc = {0.f, 0.f, 0.f, 0.f};
#pragma unroll
                for (int kt = 0; kt < 4; ++kt) {
                    bf16x8 aH = *(const bf16x8*)(ah + kt * 32);
                    bf16x8 aL = *(const bf16x8*)(al + kt * 32);
                    bf16x8 bH = *(const bf16x8*)(bh + kt * 32);
                    bf16x8 bL = *(const bf16x8*)(bl + kt * 32);
                    acc = __builtin_amdgcn_mfma_f32_16x16x32_bf16(aH, bH, acc, 0, 0, 0);
                    acc = __builtin_amdgcn_mfma_f32_16x16x32_bf16(aH, bL, acc, 0, 0, 0);
                    acc = __builtin_amdgcn_mfma_f32_16x16x32_bf16(aL, bH, acc, 0, 0, 0);
                }
                float* Pk = P + (size_t)kc * (NN * DD);
                int row0 = mt * 16 + quad * 4;
                int col = nt * 16 + m;
#pragma unroll
                for (int r = 0; r < 4; ++r) Pk[(row0 + r) * DD + col] = acc[r];
            }
        }
        gridbar(barCnt, ++ep);

        // ---- gate + h-update + next-stage GEMM (256 tasks == 256 blocks, row-local)
        {
            int m0 = bx * 4;
#pragma unroll
            for (int e2 = tid; e2 < 512; e2 += 256) {
                int r = e2 >> 7, dd = e2 & 127;
                int idx = (m0 + r) * DD + dd;
                float s = 0.f;
#pragma unroll
                for (int c = 0; c < 8; ++c) s += P[(size_t)c * (NN * DD) + idx];
                sm.g.aS[r][dd] = s;
                sm.g.uS[r][dd] = u[idx];
            }
            if (l == 2 && tid < 8) sm.g.sred[tid >> 2][tid & 3] = 0.f;
            __syncthreads();
            const float* WA = Wg + l * 32768;
            const float* WB = WA + DD * DD;
            int r0 = half * 2;
            float acc[2] = {0.f, 0.f};
#pragma unroll 4
            for (int k4 = 0; k4 < DD; k4 += 4) {
                f32x4 u0 = *(const f32x4*)&sm.g.uS[r0][k4];
                f32x4 u1 = *(const f32x4*)&sm.g.uS[r0 + 1][k4];
                f32x4 a0 = *(const f32x4*)&sm.g.aS[r0][k4];
                f32x4 a1 = *(const f32x4*)&sm.g.aS[r0 + 1][k4];
#pragma unroll
                for (int kk = 0; kk < 4; ++kk) {
                    float wa = WA[(k4 + kk) * DD + d];
                    float wb = WB[(k4 + kk) * DD + d];
                    acc[0] = fmaf(u0[kk], wa, fmaf(a0[kk], wb, acc[0]));
                    acc[1] = fmaf(u1[kk], wa, fmaf(a1[kk], wb, acc[1]));
                }
            }
            float bgd = bg[l * 128 + d];
#pragma unroll
            for (int rr = 0; rr < 2; ++rr) {
                int r = r0 + rr;
                float g = 1.f / (1.f + __expf(-(acc[rr] + bgd)));
                float nh = fmaf(g, sm.g.aS[r][d], h[(m0 + r) * DD + d]);
                nh = nh > 0.f ? nh : 0.f;
                if (l < 2) h[(m0 + r) * DD + d] = nh;
                sm.g.hS[r][d] = nh;
            }
            __syncthreads();
            const float* W2 = (l < 2) ? ((half ? Wv : Wu) + (l + 1) * 16384)
                                      : (Wc1 + (half ? DD * DD : 0));
            float av[4] = {0.f, 0.f, 0.f, 0.f};
#pragma unroll 4
            for (int k4 = 0; k4 < DD; k4 += 4) {
                f32x4 h0 = *(const f32x4*)&sm.g.hS[0][k4];
                f32x4 h1 = *(const f32x4*)&sm.g.hS[1][k4];
                f32x4 h2 = *(const f32x4*)&sm.g.hS[2][k4];
                f32x4 h3 = *(const f32x4*)&sm.g.hS[3][k4];
#pragma unroll
                for (int kk = 0; kk < 4; ++kk) {
                    float w = W2[(k4 + kk) * DD + d];
                    av[0] = fmaf(h0[kk], w, av[0]);
                    av[1] = fmaf(h1[kk], w, av[1]);
                    av[2] = fmaf(h2[kk], w, av[2]);
                    av[3] = fmaf(h3[kk], w, av[3]);
                }
            }
            if (l < 2) {
                if (half == 0) {
                    float bb = bu[(l + 1) * 128 + d];
#pragma unroll
                    for (int r = 0; r < 4; ++r) u[(m0 + r) * DD + d] = av[r] + bb;
                } else {
                    float bb = bv[(l + 1) * 128 + d];
                    float v0 = av[0] + bb, v1 = av[1] + bb, v2 = av[2] + bb, v3 = av[3] + bb;
                    ushort4 hv, lv;
                    hv.x = f2bf(v0); lv.x = f2bf(v0 - us2f(hv.x));
                    hv.y = f2bf(v1); lv.y = f2bf(v1 - us2f(hv.y));
                    hv.z = f2bf(v2); lv.z = f2bf(v2 - us2f(hv.z));
                    hv.w = f2bf(v3); lv.w = f2bf(v3 - us2f(hv.w));
                    *(ushort4*)(vTh + d * NN + m0) = hv;
                    *(ushort4*)(vTl + d * NN + m0) = lv;
                }
            } else {
                float wv = Wc2[d];
                float bcv = half ? 0.f : bc1[d];
                float* out2 = half ? hj : hi;
                int lane = tid & 63;
#pragma unroll
                for (int r = 0; r < 4; ++r) {
                    float val = av[r] + bcv;
                    out2[(m0 + r) * DD + d] = val;
                    float p = val * wv;
#pragma unroll
                    for (int off = 32; off; off >>= 1) p += __shfl_down(p, off);
                    if (lane == 0) atomicAdd(&sm.g.sred[half][r], p);
                }
                __syncthreads();
                if (tid < 4) S1[m0 + tid] = sm.g.sred[0][tid];
                else if (tid < 8) S2[m0 + tid - 4] = sm.g.sred[1][tid - 4];
            }
        }
        gridbar(barCnt, ++ep);
    }

    // ---------------- edge classifier: 64x64 logits tile per block + loss partial
    {
        int i0 = (bx >> 4) * 64, j0 = (bx & 15) * 64;
        if (tid == 0) sm.e.lred = 0.f;
        if (tid < 128) sm.e.wS[tid] = Wc2[tid];
        for (int e2 = tid; e2 < 64 * 128; e2 += 256) {
            int r = e2 >> 7, hh = e2 & 127;
            sm.e.hiT[hh][r] = hi[(i0 + r) * DD + hh];
            sm.e.hjT[hh][r] = hj[(j0 + r) * DD + hh];
        }
        __syncthreads();
        int tx = tid & 15, ty = tid >> 4;
        float acc[4][4] = {};
#pragma unroll 4
        for (int hh = 0; hh < 128; ++hh) {
            f32x4 a = *(const f32x4*)&sm.e.hiT[hh][ty * 4];
            f32x4 b = *(const f32x4*)&sm.e.hjT[hh][tx * 4];
            float w = sm.e.wS[hh];
#pragma unroll
            for (int p = 0; p < 4; ++p)
#pragma unroll
                for (int q = 0; q < 4; ++q) {
                    float x = a[p] + b[q];
                    acc[p][q] = fmaf(fabsf(x), w, acc[p][q]);
                }
        }
        float bcv = bc2[0];
        float ls = 0.f;
#pragma unroll
        for (int p = 0; p < 4; ++p) {
            int i = i0 + ty * 4 + p;
            float s1 = S1[i];
            int jb = j0 + tx * 4;
            f32x4 s2 = *(const f32x4*)(S2 + jb);
            f32x4 lg;
#pragma unroll
            for (int q = 0; q < 4; ++q)
                lg[q] = fmaf(0.5f, acc[p][q] + s1 + s2[q], bcv);
            *(f32x4*)(outL + (size_t)i * NN + jb) = lg;
            f32x4 a4 = *(const f32x4*)(adj + (size_t)i * NN + jb);
            f32x4 e4 = *(const f32x4*)(ew + (size_t)i * NN + jb);
#pragma unroll
            for (int q = 0; q < 4; ++q) {
                float t = fmaf(lg[q], a4[q], -e4[q]);
                ls = fmaf(t, t, ls);
            }
        }
#pragma unroll
        for (int off = 32; off; off >>= 1) ls += __shfl_down(ls, off);
        if ((tid & 63) == 0) atomicAdd(&sm.e.lred, ls);
        __syncthreads();
        if (tid == 0) atomicAdd(lossAcc, sm.e.lred);
    }
    gridbar(barCnt, ++ep);

    if (bx == 0 && tid == 0)
        outL[(size_t)NN * NN] =
            __hip_atomic_load(lossAcc, __ATOMIC_RELAXED, __HIP_MEMORY_SCOPE_AGENT) *
            (1.f / (1024.f * 1024.f));
}

extern "C" void kernel_launch(void* const* d_in, const int* in_sizes, int n_in,
                              void* d_out, int out_size, void* d_ws, size_t ws_size,
                              hipStream_t stream)
{
    const float* nf  = (const float*)d_in[0];
    const float* adj = (const float*)d_in[1];
    const float* ew  = (const float*)d_in[2];
    const float* We  = (const float*)d_in[3];
    const float* be  = (const float*)d_in[4];
    const float* Wu  = (const float*)d_in[5];
    const float* bu  = (const float*)d_in[6];
    const float* Wv  = (const float*)d_in[7];
    const float* bv  = (const float*)d_in[8];
    const float* Wg  = (const float*)d_in[9];
    const float* bg  = (const float*)d_in[10];
    const float* Wc1 = (const float*)d_in[11];
    const float* bc1 = (const float*)d_in[12];
    const float* Wc2 = (const float*)d_in[13];
    const float* bc2 = (const float*)d_in[14];

    float* ws = (float*)d_ws;
    float* h   = ws;                                          // 131072
    float* u   = ws + 131072;                                 // 131072
    unsigned short* vTh = (unsigned short*)(ws + 262144);     // 131072 bf16
    unsigned short* vTl = (unsigned short*)(ws + 327680);     // 131072 bf16
    float* P   = ws + 393216;                                 // 8 x 131072
    unsigned short* adjH = (unsigned short*)(ws + 1441792);   // 1M bf16
    unsigned short* adjL = (unsigned short*)(ws + 1966080);   // 1M bf16
    float* hi  = ws + 2490368;                                // 131072
    float* hj  = ws + 2621440;                                // 131072
    float* S1  = ws + 2752512;                                // 1024
    float* S2  = ws + 2753536;                                // 1024
    float* lossAcc = ws + 2754560;                            // 1 (+pad)
    unsigned* barCnt = (unsigned*)(ws + 2754592);             // 16 counters x 32 uints (128B lines)

    // zero lossAcc + barrier counters (544 floats = 2176 B), capture-legal
    hipMemsetAsync((void*)lossAcc, 0, 2176, stream);
    k_fused<<<NBLK, 256, 0, stream>>>(adj, ew, nf, We, be, Wu, bu, Wv, bv, Wg, bg,
                                      Wc1, bc1, Wc2, bc2, h, u, vTh, vTl, P,
                                      adjH, adjL, hi, hj, S1, S2,
                                      lossAcc, barCnt, (float*)d_out);
}

// Round 2
// 263.156 us; speedup vs baseline: 2.1217x; 2.1217x over previous
//
#include <hip/hip_runtime.h>

#define NN 1024
#define DD 128
#define NBLK 256

typedef __attribute__((ext_vector_type(8))) __bf16 bf16x8;
typedef __attribute__((ext_vector_type(4))) float f32x4;

__device__ __forceinline__ float us2f(unsigned short b) { return __uint_as_float(((unsigned)b) << 16); }
__device__ __forceinline__ unsigned short f2bf(float f) {
    unsigned x = __float_as_uint(f);
    return (unsigned short)((x + 0x7fffu + ((x >> 16) & 1u)) >> 16);   // RNE
}

// Grid barrier v2. Layout in bar[]: sub-counters at [0,32,..,480] (one 128B line each,
// 16 blocks feed each), master at [512], publish flag at [544].
// - tid0-only: fence (buffer_wbl2 -> data at IC) THEN relaxed arrival atomic.
// - Polling uses RELAXED agent loads (no per-iteration cache invalidate!) on ONE flag
//   line; a single acquire fence after loop exit invalidates stale L1/L2 once.
// All 256 blocks co-resident (grid == #CUs, 70KB LDS => 2 blocks/CU cap), so spin is safe.
__device__ __forceinline__ void gridbar(unsigned* bar, unsigned ep) {
    __syncthreads();
    if (threadIdx.x == 0) {
        __threadfence();   // release: drain this block's stores to the coherence point
        unsigned old = __hip_atomic_fetch_add(&bar[(blockIdx.x & 15) << 5], 1u,
                                              __ATOMIC_RELAXED, __HIP_MEMORY_SCOPE_AGENT);
        if (old == (ep << 4) - 1) {                    // this sub-counter complete for epoch ep
            unsigned mold = __hip_atomic_fetch_add(&bar[512], 1u,
                                                   __ATOMIC_RELAXED, __HIP_MEMORY_SCOPE_AGENT);
            if (mold == (ep << 4) - 1)                 // all 16 sub-counters complete
                __hip_atomic_store(&bar[544], ep, __ATOMIC_RELAXED, __HIP_MEMORY_SCOPE_AGENT);
        }
        while (__hip_atomic_load(&bar[544], __ATOMIC_RELAXED, __HIP_MEMORY_SCOPE_AGENT) < ep)
            __builtin_amdgcn_s_sleep(4);
        __threadfence();   // acquire: invalidate stale cached lines before reading others' data
    }
    __syncthreads();
}

__global__ __launch_bounds__(256) void k_fused(
    const float* __restrict__ adj, const float* __restrict__ ew,
    const float* __restrict__ nf, const float* __restrict__ We, const float* __restrict__ be,
    const float* __restrict__ Wu, const float* __restrict__ bu,
    const float* __restrict__ Wv, const float* __restrict__ bv,
    const float* __restrict__ Wg, const float* __restrict__ bg,
    const float* __restrict__ Wc1, const float* __restrict__ bc1,
    const float* __restrict__ Wc2, const float* __restrict__ bc2,
    float* __restrict__ h, float* __restrict__ u,
    unsigned short* __restrict__ vTh, unsigned short* __restrict__ vTl,
    float* __restrict__ P,
    unsigned short* __restrict__ adjH, unsigned short* __restrict__ adjL,
    float* __restrict__ hi, float* __restrict__ hj,
    float* __restrict__ S1, float* __restrict__ S2,
    float* __restrict__ lossAcc, unsigned* __restrict__ counter,
    unsigned* __restrict__ barCnt, float* __restrict__ outL)
{
    __shared__ union SMem {
        float hS4[4][DD];                                              // phase 0 (embed)
        struct { float uS[4][DD], aS[4][DD], hS[4][DD], sred[2][4]; } g;  // gate phases
        struct { float hiT[128][68], hjT[128][68], wS[128], lred; } e;    // edge phase
    } sm;

    int tid = threadIdx.x;
    int bx = blockIdx.x;
    int d = tid & 127, half = tid >> 7;
    unsigned ep = 0;

    // ---------------- Phase 0: adj -> bf16 split (tasks 0..1023) | embed + layer-0 u/v (tasks 1024..1279)
    for (int t = bx; t < 1280; t += NBLK) {
        if (t < 1024) {
            int idx = (t * 256 + tid) * 4;
            float4 a = *(const float4*)(adj + idx);
            ushort4 hv, lv;
            hv.x = f2bf(a.x); lv.x = f2bf(a.x - us2f(hv.x));
            hv.y = f2bf(a.y); lv.y = f2bf(a.y - us2f(hv.y));
            hv.z = f2bf(a.z); lv.z = f2bf(a.z - us2f(hv.z));
            hv.w = f2bf(a.w); lv.w = f2bf(a.w - us2f(hv.w));
            *(ushort4*)(adjH + idx) = hv;
            *(ushort4*)(adjL + idx) = lv;
        } else {
            int m0 = (t - 1024) * 4;
            float hr[4];
#pragma unroll
            for (int r = 0; r < 4; ++r) {
                float a = be[d];
#pragma unroll
                for (int k = 0; k < 3; ++k) a = fmaf(nf[(m0 + r) * 3 + k], We[k * DD + d], a);
                hr[r] = a;
            }
            if (half == 0) {
#pragma unroll
                for (int r = 0; r < 4; ++r) { h[(m0 + r) * DD + d] = hr[r]; sm.hS4[r][d] = hr[r]; }
            }
            __syncthreads();
            const float* W = half ? Wv : Wu;
            float acc[4] = {0.f, 0.f, 0.f, 0.f};
#pragma unroll 4
            for (int k4 = 0; k4 < DD; k4 += 4) {
                f32x4 h0 = *(const f32x4*)&sm.hS4[0][k4];
                f32x4 h1 = *(const f32x4*)&sm.hS4[1][k4];
                f32x4 h2 = *(const f32x4*)&sm.hS4[2][k4];
                f32x4 h3 = *(const f32x4*)&sm.hS4[3][k4];
#pragma unroll
                for (int kk = 0; kk < 4; ++kk) {
                    float w = W[(k4 + kk) * DD + d];
                    acc[0] = fmaf(h0[kk], w, acc[0]);
                    acc[1] = fmaf(h1[kk], w, acc[1]);
                    acc[2] = fmaf(h2[kk], w, acc[2]);
                    acc[3] = fmaf(h3[kk], w, acc[3]);
                }
            }
            if (half == 0) {
                float bb = bu[d];
#pragma unroll
                for (int r = 0; r < 4; ++r) u[(m0 + r) * DD + d] = acc[r] + bb;
            } else {
                float bb = bv[d];
                float v0 = acc[0] + bb, v1 = acc[1] + bb, v2 = acc[2] + bb, v3 = acc[3] + bb;
                ushort4 hv, lv;
                hv.x = f2bf(v0); lv.x = f2bf(v0 - us2f(hv.x));
                hv.y = f2bf(v1); lv.y = f2bf(v1 - us2f(hv.y));
                hv.z = f2bf(v2); lv.z = f2bf(v2 - us2f(hv.z));
                hv.w = f2bf(v3); lv.w = f2bf(v3 - us2f(hv.w));
                *(ushort4*)(vTh + d * NN + m0) = hv;
                *(ushort4*)(vTl + d * NN + m0) = lv;
            }
        }
    }
    gridbar(barCnt, ++ep);

    // ---------------- 3 GCN layers
    for (int l = 0; l < 3; ++l) {
        // ---- agg partials: P[kc] = adj[:, kc-chunk] @ v[kc-chunk, :]  (1024 tasks, MFMA split-precision)
        {
            int lane = tid & 63, w = tid >> 6;
            for (int t = bx; t < 1024; t += NBLK) {
                int nt = t >> 7;
                int mt = (t >> 1) & 63;
                int kc = ((t & 1) << 2) | w;
                int m = lane & 15, quad = lane >> 4;
                int k0 = kc * 128 + quad * 8;
                const unsigned short* ah = adjH + (size_t)(mt * 16 + m) * NN + k0;
                const unsigned short* al = adjL + (size_t)(mt * 16 + m) * NN + k0;
                const unsigned short* bh = vTh + (size_t)(nt * 16 + m) * NN + k0;
                const unsigned short* bl = vTl + (size_t)(nt * 16 + m) * NN + k0;
                f32x4 acc = {0.f, 0.f, 0.f, 0.f};
#pragma unroll
                for (int kt = 0; kt < 4; ++kt) {
                    bf16x8 aH = *(const bf16x8*)(ah + kt * 32);
                    bf16x8 aL = *(const bf16x8*)(al + kt * 32);
                    bf16x8 bH = *(const bf16x8*)(bh + kt * 32);
                    bf16x8 bL = *(const bf16x8*)(bl + kt * 32);
                    acc = __builtin_amdgcn_mfma_f32_16x16x32_bf16(aH, bH, acc, 0, 0, 0);
                    acc = __builtin_amdgcn_mfma_f32_16x16x32_bf16(aH, bL, acc, 0, 0, 0);
                    acc = __builtin_amdgcn_mfma_f32_16x16x32_bf16(aL, bH, acc, 0, 0, 0);
                }
                float* Pk = P + (size_t)kc * (NN * DD);
                int row0 = mt * 16 + quad * 4;
                int col = nt * 16 + m;
#pragma unroll
                for (int r = 0; r < 4; ++r) Pk[(row0 + r) * DD + col] = acc[r];
            }
        }
        gridbar(barCnt, ++ep);

        // ---- gate + h-update + next-stage GEMM (256 tasks == 256 blocks, row-local)
        {
            int m0 = bx * 4;
#pragma unroll
            for (int e2 = tid; e2 < 512; e2 += 256) {
                int r = e2 >> 7, dd = e2 & 127;
                int idx = (m0 + r) * DD + dd;
                float s = 0.f;
#pragma unroll
                for (int c = 0; c < 8; ++c) s += P[(size_t)c * (NN * DD) + idx];
                sm.g.aS[r][dd] = s;
                sm.g.uS[r][dd] = u[idx];
            }
            if (l == 2 && tid < 8) sm.g.sred[tid >> 2][tid & 3] = 0.f;
            __syncthreads();
            const float* WA = Wg + l * 32768;
            const float* WB = WA + DD * DD;
            int r0 = half * 2;
            float acc[2] = {0.f, 0.f};
#pragma unroll 4
            for (int k4 = 0; k4 < DD; k4 += 4) {
                f32x4 u0 = *(const f32x4*)&sm.g.uS[r0][k4];
                f32x4 u1 = *(const f32x4*)&sm.g.uS[r0 + 1][k4];
                f32x4 a0 = *(const f32x4*)&sm.g.aS[r0][k4];
                f32x4 a1 = *(const f32x4*)&sm.g.aS[r0 + 1][k4];
#pragma unroll
                for (int kk = 0; kk < 4; ++kk) {
                    float wa = WA[(k4 + kk) * DD + d];
                    float wb = WB[(k4 + kk) * DD + d];
                    acc[0] = fmaf(u0[kk], wa, fmaf(a0[kk], wb, acc[0]));
                    acc[1] = fmaf(u1[kk], wa, fmaf(a1[kk], wb, acc[1]));
                }
            }
            float bgd = bg[l * 128 + d];
#pragma unroll
            for (int rr = 0; rr < 2; ++rr) {
                int r = r0 + rr;
                float g = 1.f / (1.f + __expf(-(acc[rr] + bgd)));
                float nh = fmaf(g, sm.g.aS[r][d], h[(m0 + r) * DD + d]);
                nh = nh > 0.f ? nh : 0.f;
                if (l < 2) h[(m0 + r) * DD + d] = nh;
                sm.g.hS[r][d] = nh;
            }
            __syncthreads();
            const float* W2 = (l < 2) ? ((half ? Wv : Wu) + (l + 1) * 16384)
                                      : (Wc1 + (half ? DD * DD : 0));
            float av[4] = {0.f, 0.f, 0.f, 0.f};
#pragma unroll 4
            for (int k4 = 0; k4 < DD; k4 += 4) {
                f32x4 h0 = *(const f32x4*)&sm.g.hS[0][k4];
                f32x4 h1 = *(const f32x4*)&sm.g.hS[1][k4];
                f32x4 h2 = *(const f32x4*)&sm.g.hS[2][k4];
                f32x4 h3 = *(const f32x4*)&sm.g.hS[3][k4];
#pragma unroll
                for (int kk = 0; kk < 4; ++kk) {
                    float w = W2[(k4 + kk) * DD + d];
                    av[0] = fmaf(h0[kk], w, av[0]);
                    av[1] = fmaf(h1[kk], w, av[1]);
                    av[2] = fmaf(h2[kk], w, av[2]);
                    av[3] = fmaf(h3[kk], w, av[3]);
                }
            }
            if (l < 2) {
                if (half == 0) {
                    float bb = bu[(l + 1) * 128 + d];
#pragma unroll
                    for (int r = 0; r < 4; ++r) u[(m0 + r) * DD + d] = av[r] + bb;
                } else {
                    float bb = bv[(l + 1) * 128 + d];
                    float v0 = av[0] + bb, v1 = av[1] + bb, v2 = av[2] + bb, v3 = av[3] + bb;
                    ushort4 hv, lv;
                    hv.x = f2bf(v0); lv.x = f2bf(v0 - us2f(hv.x));
                    hv.y = f2bf(v1); lv.y = f2bf(v1 - us2f(hv.y));
                    hv.z = f2bf(v2); lv.z = f2bf(v2 - us2f(hv.z));
                    hv.w = f2bf(v3); lv.w = f2bf(v3 - us2f(hv.w));
                    *(ushort4*)(vTh + d * NN + m0) = hv;
                    *(ushort4*)(vTl + d * NN + m0) = lv;
                }
            } else {
                float wv = Wc2[d];
                float bcv = half ? 0.f : bc1[d];
                float* out2 = half ? hj : hi;
                int lane = tid & 63;
#pragma unroll
                for (int r = 0; r < 4; ++r) {
                    float val = av[r] + bcv;
                    out2[(m0 + r) * DD + d] = val;
                    float p = val * wv;
#pragma unroll
                    for (int off = 32; off; off >>= 1) p += __shfl_down(p, off);
                    if (lane == 0) atomicAdd(&sm.g.sred[half][r], p);
                }
                __syncthreads();
                if (tid < 4) S1[m0 + tid] = sm.g.sred[0][tid];
                else if (tid < 8) S2[m0 + tid - 4] = sm.g.sred[1][tid - 4];
            }
        }
        gridbar(barCnt, ++ep);
    }

    // ---------------- edge classifier: 64x64 logits tile per block + loss partial; no final
    // barrier -- last-to-finish block (atomic counter) finalizes the loss scalar.
    {
        int i0 = (bx >> 4) * 64, j0 = (bx & 15) * 64;
        if (tid == 0) sm.e.lred = 0.f;
        if (tid < 128) sm.e.wS[tid] = Wc2[tid];
        for (int e2 = tid; e2 < 64 * 128; e2 += 256) {
            int r = e2 >> 7, hh = e2 & 127;
            sm.e.hiT[hh][r] = hi[(i0 + r) * DD + hh];
            sm.e.hjT[hh][r] = hj[(j0 + r) * DD + hh];
        }
        __syncthreads();
        int tx = tid & 15, ty = tid >> 4;
        float acc[4][4] = {};
#pragma unroll 4
        for (int hh = 0; hh < 128; ++hh) {
            f32x4 a = *(const f32x4*)&sm.e.hiT[hh][ty * 4];
            f32x4 b = *(const f32x4*)&sm.e.hjT[hh][tx * 4];
            float w = sm.e.wS[hh];
#pragma unroll
            for (int p = 0; p < 4; ++p)
#pragma unroll
                for (int q = 0; q < 4; ++q) {
                    float x = a[p] + b[q];
                    acc[p][q] = fmaf(fabsf(x), w, acc[p][q]);
                }
        }
        float bcv = bc2[0];
        float ls = 0.f;
#pragma unroll
        for (int p = 0; p < 4; ++p) {
            int i = i0 + ty * 4 + p;
            float s1 = S1[i];
            int jb = j0 + tx * 4;
            f32x4 s2 = *(const f32x4*)(S2 + jb);
            f32x4 lg;
#pragma unroll
            for (int q = 0; q < 4; ++q)
                lg[q] = fmaf(0.5f, acc[p][q] + s1 + s2[q], bcv);
            *(f32x4*)(outL + (size_t)i * NN + jb) = lg;
            f32x4 a4 = *(const f32x4*)(adj + (size_t)i * NN + jb);
            f32x4 e4 = *(const f32x4*)(ew + (size_t)i * NN + jb);
#pragma unroll
            for (int q = 0; q < 4; ++q) {
                float t = fmaf(lg[q], a4[q], -e4[q]);
                ls = fmaf(t, t, ls);
            }
        }
#pragma unroll
        for (int off = 32; off; off >>= 1) ls += __shfl_down(ls, off);
        if ((tid & 63) == 0) atomicAdd(&sm.e.lred, ls);
        __syncthreads();
        if (tid == 0) {
            atomicAdd(lossAcc, sm.e.lred);
            __threadfence();
            unsigned old = atomicAdd(counter, 1u);
            if (old == NBLK - 1u) {
                __threadfence();
                outL[(size_t)NN * NN] = (*(volatile float*)lossAcc) * (1.f / (1024.f * 1024.f));
            }
        }
    }
}

extern "C" void kernel_launch(void* const* d_in, const int* in_sizes, int n_in,
                              void* d_out, int out_size, void* d_ws, size_t ws_size,
                              hipStream_t stream)
{
    const float* nf  = (const float*)d_in[0];
    const float* adj = (const float*)d_in[1];
    const float* ew  = (const float*)d_in[2];
    const float* We  = (const float*)d_in[3];
    const float* be  = (const float*)d_in[4];
    const float* Wu  = (const float*)d_in[5];
    const float* bu  = (const float*)d_in[6];
    const float* Wv  = (const float*)d_in[7];
    const float* bv  = (const float*)d_in[8];
    const float* Wg  = (const float*)d_in[9];
    const float* bg  = (const float*)d_in[10];
    const float* Wc1 = (const float*)d_in[11];
    const float* bc1 = (const float*)d_in[12];
    const float* Wc2 = (const float*)d_in[13];
    const float* bc2 = (const float*)d_in[14];

    float* ws = (float*)d_ws;
    float* h   = ws;                                          // 131072
    float* u   = ws + 131072;                                 // 131072
    unsigned short* vTh = (unsigned short*)(ws + 262144);     // 131072 bf16
    unsigned short* vTl = (unsigned short*)(ws + 327680);     // 131072 bf16
    float* P   = ws + 393216;                                 // 8 x 131072
    unsigned short* adjH = (unsigned short*)(ws + 1441792);   // 1M bf16
    unsigned short* adjL = (unsigned short*)(ws + 1966080);   // 1M bf16
    float* hi  = ws + 2490368;                                // 131072
    float* hj  = ws + 2621440;                                // 131072
    float* S1  = ws + 2752512;                                // 1024
    float* S2  = ws + 2753536;                                // 1024
    float* lossAcc = ws + 2754560;                            // 1
    unsigned* counter = (unsigned*)(ws + 2754561);            // 1
    unsigned* barCnt = (unsigned*)(ws + 2754592);             // 545 uints (sub/master/flag)

    // zero lossAcc + finalize counter + barrier state (capture-legal)
    hipMemsetAsync((void*)lossAcc, 0, 2560, stream);
    k_fused<<<NBLK, 256, 0, stream>>>(adj, ew, nf, We, be, Wu, bu, Wv, bv, Wg, bg,
                                      Wc1, bc1, Wc2, bc2, h, u, vTh, vTl, P,
                                      adjH, adjL, hi, hj, S1, S2,
                                      lossAcc, counter, barCnt, (float*)d_out);
}